// Round 1
// 243.273 us; speedup vs baseline: 1.0427x; 1.0427x over previous
//
#include <hip/hip_runtime.h>

// RGCN: N=50000, E=1.6M, R=8, 128 -> 64 -> 64.
// R13 = R12 (253.7us) with latency/serialization cuts:
//   - agg_csr rewrite: no ds_bpermute chain (offs loaded per-lane w/ 8-way
//     broadcast; per-(dst,rel) count packed into record bits 25..31, weight
//     recovered via v_rcp); 32 edges/step => 4 gathers in flight per lane.
//   - inv[] table deleted (finalize no longer writes it, agg no longer reads).
//   - bucket_append fused into the gemm1 dispatch (independent work): append
//     blocks [0,391) + gemm blocks [391,1173), union'd dynamic LDS 52224B,
//     same 3 blocks/CU as standalone gemm1. One fewer dispatch.

constexpr int NN  = 50000;
constexpr int NE  = 1600000;
constexpr int NR  = 8;
constexpr int FIN = 128;
constexpr int FH  = 64;

constexpr int BSH = 7;                       // 128 dst nodes per bucket
constexpr int BN  = 1 << BSH;
constexpr int NB  = (NN + BN - 1) >> BSH;    // 391
constexpr int CAP = 6144;                    // bucket capacity (load ~4092±64)
constexpr int CH  = 4096;                    // edges per append block
constexpr int NAPP = (NE + CH - 1) / CH;     // 391 append blocks
constexpr unsigned XWMAX = (unsigned)(NN - 1) * (NR * 64) + (NR - 1) * 64;

typedef __attribute__((ext_vector_type(8))) short bf16x8;
typedef __attribute__((ext_vector_type(4))) float f32x4;

__device__ __forceinline__ unsigned short f2bf(float f) {
  unsigned u = __float_as_uint(f);
  u = (u + 0x7fff + ((u >> 16) & 1)) >> 16;   // RNE
  return (unsigned short)u;
}
__device__ __forceinline__ float bf2f(unsigned short b) {
  return __uint_as_float(((unsigned)b) << 16);
}
__device__ __forceinline__ bool edge_ok(unsigned s, unsigned d, unsigned r) {
  return s < NN && d < NN && r < NR;
}

// ---------------- CSR build: append (device body, LDS via pointer) ----------
// Block-staged append: per-block LDS hist, one global atomic per
// (block,bucket) span reservation, LDS-staged bucket-grouped records,
// coalesced 4B-packed write-out into fixed-capacity bucket windows.
// LDS layout: stage[CH] (32768B) | h[NB] | gbase[NB] | sbase[NB] | scur[NB] | wtot[4]
__device__ void append_body(char* smem, int bx,
                            const int* __restrict__ src,
                            const int* __restrict__ dst,
                            const int* __restrict__ et,
                            int* __restrict__ bcur,
                            unsigned* __restrict__ brecs) {
  uint2* stage = (uint2*)smem;
  int* h     = (int*)(smem + (size_t)CH * 8);
  int* gbase = h + NB;
  int* sbase = gbase + NB;
  int* scur  = sbase + NB;
  int* wtot  = scur + NB;

  const int t  = threadIdx.x;
  const int c0 = bx * CH;
  const int m  = min(CH, NE - c0);

  for (int i = t; i < NB; i += 256) h[i] = 0;
  __syncthreads();

  // pass A: per-block bucket histogram
  for (int i = t; i < m; i += 256) {
    const unsigned s = (unsigned)src[c0 + i];
    const unsigned d = (unsigned)dst[c0 + i];
    const unsigned r = (unsigned)et[c0 + i];
    if (edge_ok(s, d, r)) atomicAdd(&h[d >> BSH], 1);
  }
  __syncthreads();

  // reserve spans + block-local exclusive scan (2 buckets per thread)
  const int v0 = (2 * t < NB) ? h[2 * t] : 0;
  const int v1 = (2 * t + 1 < NB) ? h[2 * t + 1] : 0;
  if (2 * t < NB     && v0) gbase[2 * t]     = atomicAdd(&bcur[2 * t], v0);
  if (2 * t + 1 < NB && v1) gbase[2 * t + 1] = atomicAdd(&bcur[2 * t + 1], v1);
  const int s = v0 + v1;
  int incl = s;
#pragma unroll
  for (int o = 1; o < 64; o <<= 1) {
    int u = __shfl_up(incl, o, 64);
    if ((t & 63) >= o) incl += u;
  }
  if ((t & 63) == 63) wtot[t >> 6] = incl;
  __syncthreads();
  int wo = 0;
  for (int w = 0; w < (t >> 6); ++w) wo += wtot[w];
  const int e = wo + incl - s;
  if (2 * t < NB)     { sbase[2 * t] = e;          scur[2 * t] = e; }
  if (2 * t + 1 < NB) { sbase[2 * t + 1] = e + v0; scur[2 * t + 1] = e + v0; }
  __syncthreads();

  // pass B: stage records grouped by bucket
  for (int i = t; i < m; i += 256) {
    const unsigned sv = (unsigned)src[c0 + i];
    const unsigned d  = (unsigned)dst[c0 + i];
    const unsigned r  = (unsigned)et[c0 + i];
    if (edge_ok(sv, d, r)) {
      const int p = atomicAdd(&scur[d >> BSH], 1);
      if (p < CH) stage[p] = make_uint2((sv << 10) | (((unsigned)d & (BN - 1)) << 3) | r, d);
    }
  }
  __syncthreads();

  // write-out: consecutive j -> consecutive global addresses (4B packed)
  const int M = min(sbase[NB - 1] + h[NB - 1], CH);
  for (int j = t; j < M; j += 256) {
    const uint2 rec = stage[j];
    const int b = (int)(rec.y >> BSH);
    const int idx = min(gbase[b] + (j - sbase[b]), NB * CAP - 1);
    brecs[idx] = rec.x;
  }
}

// One block per bucket: count per (dlocal, r) in LDS, scan, emit
// deg/row_start, place final 4B records (cnt<<25 | sv<<9 | r<<6) into the
// bucket window. Weight = 1/cnt recovered in agg via v_rcp; no inv[] table.
__global__ void __launch_bounds__(256) bucket_finalize(
    const int* __restrict__ bcur, const unsigned* __restrict__ brecs,
    int* __restrict__ row_start, int* __restrict__ deg,
    unsigned* __restrict__ recs) {
  const int b    = blockIdx.x;
  const int base = b * CAP;
  const int m    = min(bcur[b] - base, CAP);
  const int d0   = b << BSH;
  __shared__ int cnt[BN * NR];
  __shared__ int curs[BN * NR];
  __shared__ int wtot[4];
  const int t = threadIdx.x;

  for (int i = t; i < BN * NR; i += 256) cnt[i] = 0;
  __syncthreads();
  for (int i = t; i < m; i += 256) {
    const unsigned rec = brecs[base + i];
    const int dl = (int)((rec >> 3) & (BN - 1));
    const int r  = (int)(rec & 7);
    atomicAdd(&cnt[dl * NR + r], 1);
  }
  __syncthreads();

  const int c0 = cnt[t * 4], c1 = cnt[t * 4 + 1], c2 = cnt[t * 4 + 2], c3 = cnt[t * 4 + 3];
  const int s = c0 + c1 + c2 + c3;
  int incl = s;
#pragma unroll
  for (int o = 1; o < 64; o <<= 1) {
    int u = __shfl_up(incl, o, 64);
    if ((t & 63) >= o) incl += u;
  }
  if ((t & 63) == 63) wtot[t >> 6] = incl;
  __syncthreads();
  int wo = 0;
  for (int w = 0; w < (t >> 6); ++w) wo += wtot[w];
  const int e = wo + incl - s;
  curs[t * 4]     = e;
  curs[t * 4 + 1] = e + c0;
  curs[t * 4 + 2] = e + c0 + c1;
  curs[t * 4 + 3] = e + c0 + c1 + c2;
  __syncthreads();

  if (t < BN) {
    const int d = d0 + t;
    if (d < NN) {
      const int start = curs[t * NR];
      const int end   = (t == BN - 1) ? m : curs[(t + 1) * NR];
      row_start[d] = base + start;
      deg[d]       = end - start;
    }
  }
  __syncthreads();

  for (int i = t; i < m; i += 256) {
    const unsigned rec = brecs[base + i];
    const int dl = (int)((rec >> 3) & (BN - 1));
    const int r  = (int)(rec & 7);
    const unsigned sv = rec >> 10;
    const int p  = atomicAdd(&curs[dl * NR + r], 1);
    const unsigned cn = (unsigned)min(cnt[dl * NR + r], 127);
    recs[base + min(p, CAP - 1)] = (cn << 25) | (sv << 9) | ((unsigned)r << 6);
  }
}

// ---------------- prep: bcur init + weights -> bf16 transposed ----------------
// W[g][k][n] fp32 -> Wt[g][n][k] bf16 (g<NR rel, g==NR root).
__global__ void prep(const float* __restrict__ W1r, const float* __restrict__ W1o,
                     const float* __restrict__ W2r, const float* __restrict__ W2o,
                     unsigned short* __restrict__ Wt1,
                     unsigned short* __restrict__ Wt2,
                     int* __restrict__ bcur) {
  const int i  = blockIdx.x * blockDim.x + threadIdx.x;
  if (i < NB) bcur[i] = i * CAP;
  const int n1 = (NR + 1) * 64 * FIN;
  const int n2 = (NR + 1) * 64 * FH;
  if (i < n1) {
    const int g = i / (64 * FIN), rem = i % (64 * FIN);
    const int n = rem / FIN, k = rem % FIN;
    const float* W = (g < NR) ? (W1r + (size_t)g * FIN * 64) : W1o;
    Wt1[i] = f2bf(W[k * 64 + n]);
  } else if (i < n1 + n2) {
    const int j = i - n1;
    const int g = j / (64 * FH), rem = j % (64 * FH);
    const int n = rem / FH, k = rem % FH;
    const float* W = (g < NR) ? (W2r + (size_t)g * FH * 64) : W2o;
    Wt2[j] = f2bf(W[k * 64 + n]);
  }
}

// ---------------- MFMA GEMM body (LDS via pointer, dbuf-B) ----------------
template <int K, bool A_FP32>
__device__ void gemm_body(char* smem, int bx,
                          const void* __restrict__ Av,
                          const unsigned short* __restrict__ Wt,
                          const float* __restrict__ bias,
                          unsigned short* __restrict__ xw,
                          float* __restrict__ root_out) {
  constexpr int KP  = K + 8;
  constexpr int NCH = 64 * (K / 8) / 256;   // B chunks per thread (4 / 2)
  unsigned short* As  = (unsigned short*)smem;
  unsigned short* Bs0 = As + 64 * KP;       // double buffer halves
  const int n0  = bx * 64;
  const int tid = threadIdx.x;

  if constexpr (A_FP32) {
    const float* A = (const float*)Av;
    for (int c = tid; c < 64 * (K / 8); c += 256) {
      const int row = c / (K / 8), kp = (c % (K / 8)) * 8;
      bf16x8 v = {};
      if (n0 + row < NN) {
        const float* p = A + (size_t)(n0 + row) * K + kp;
        const float4 f0 = *(const float4*)p;
        const float4 f1 = *(const float4*)(p + 4);
        v[0] = f2bf(f0.x); v[1] = f2bf(f0.y); v[2] = f2bf(f0.z); v[3] = f2bf(f0.w);
        v[4] = f2bf(f1.x); v[5] = f2bf(f1.y); v[6] = f2bf(f1.z); v[7] = f2bf(f1.w);
      }
      *(bf16x8*)(As + row * KP + kp) = v;
    }
  } else {
    const unsigned short* A = (const unsigned short*)Av;
    for (int c = tid; c < 64 * (K / 8); c += 256) {
      const int row = c / (K / 8), kp = (c % (K / 8)) * 8;
      bf16x8 v = {};
      if (n0 + row < NN) v = *(const bf16x8*)(A + (size_t)(n0 + row) * K + kp);
      *(bf16x8*)(As + row * KP + kp) = v;
    }
  }

  // stage B group 0 into buffer 0
  for (int c = 0; c < NCH; ++c) {
    const int idx = tid + c * 256;
    const int row = idx / (K / 8), kp = (idx % (K / 8)) * 8;
    *(bf16x8*)(Bs0 + row * KP + kp) = *(const bf16x8*)(Wt + idx * 8);
  }
  __syncthreads();

  const int wave = tid >> 6, lane = tid & 63;
  const int i16 = lane & 15, quad = lane >> 4;
  const int r0 = wave * 16 + i16;

  for (int g = 0; g <= NR; ++g) {
    const int buf = g & 1;
    unsigned short* Bc = Bs0 + buf * 64 * KP;         // compute buffer
    unsigned short* Bn = Bs0 + (buf ^ 1) * 64 * KP;   // next buffer
    bf16x8 breg[NCH];
    if (g < NR) {
      const unsigned short* Wn = Wt + (size_t)(g + 1) * 64 * K;
#pragma unroll
      for (int c = 0; c < NCH; ++c) breg[c] = *(const bf16x8*)(Wn + (tid + c * 256) * 8);
    }

    f32x4 acc[4] = {};
#pragma unroll
    for (int kc = 0; kc < K / 32; ++kc) {
      const int k0 = kc * 32 + quad * 8;
      const bf16x8 a0 = *(const bf16x8*)(As + r0 * KP + k0);
      const bf16x8 b0 = *(const bf16x8*)(Bc + (i16)      * KP + k0);
      const bf16x8 b1 = *(const bf16x8*)(Bc + (i16 + 16) * KP + k0);
      const bf16x8 b2 = *(const bf16x8*)(Bc + (i16 + 32) * KP + k0);
      const bf16x8 b3 = *(const bf16x8*)(Bc + (i16 + 48) * KP + k0);
      acc[0] = __builtin_amdgcn_mfma_f32_16x16x32_bf16(a0, b0, acc[0], 0, 0, 0);
      acc[1] = __builtin_amdgcn_mfma_f32_16x16x32_bf16(a0, b1, acc[1], 0, 0, 0);
      acc[2] = __builtin_amdgcn_mfma_f32_16x16x32_bf16(a0, b2, acc[2], 0, 0, 0);
      acc[3] = __builtin_amdgcn_mfma_f32_16x16x32_bf16(a0, b3, acc[3], 0, 0, 0);
    }

    if (g < NR) {
#pragma unroll
      for (int c = 0; c < NCH; ++c) {
        const int idx = tid + c * 256;
        const int row = idx / (K / 8), kp = (idx % (K / 8)) * 8;
        *(bf16x8*)(Bn + row * KP + kp) = breg[c];
      }
    }

    if (g < NR) {
#pragma unroll
      for (int reg = 0; reg < 4; ++reg) {
        const int n = n0 + wave * 16 + quad * 4 + reg;
        if (n >= NN) continue;
        unsigned short* p = xw + (size_t)n * (NR * 64) + g * 64 + i16;
#pragma unroll
        for (int ct = 0; ct < 4; ++ct) p[ct * 16] = f2bf(acc[ct][reg]);
      }
    } else {
      float bv[4];
#pragma unroll
      for (int ct = 0; ct < 4; ++ct) bv[ct] = bias[ct * 16 + i16];
#pragma unroll
      for (int reg = 0; reg < 4; ++reg) {
        const int n = n0 + wave * 16 + quad * 4 + reg;
        if (n >= NN) continue;
        float* p = root_out + (size_t)n * 64 + i16;
#pragma unroll
        for (int ct = 0; ct < 4; ++ct) p[ct * 16] = acc[ct][reg] + bv[ct];
      }
    }
    __syncthreads();
  }
}

// ---------------- fused dispatch: append (391 blocks) || gemm1 ----------------
__global__ void __launch_bounds__(256) fused_append_gemm1(
    const int* __restrict__ src, const int* __restrict__ dst,
    const int* __restrict__ et, int* __restrict__ bcur,
    unsigned* __restrict__ brecs,
    const float* __restrict__ A, const unsigned short* __restrict__ Wt,
    const float* __restrict__ bias, unsigned short* __restrict__ xw,
    float* __restrict__ root_out) {
  extern __shared__ char smem[];
  if ((int)blockIdx.x < NAPP)
    append_body(smem, (int)blockIdx.x, src, dst, et, bcur, brecs);
  else
    gemm_body<FIN, true>(smem, (int)blockIdx.x - NAPP, A, Wt, bias, xw, root_out);
}

__global__ void __launch_bounds__(256) gemm_l2(
    const unsigned short* __restrict__ A, const unsigned short* __restrict__ Wt,
    const float* __restrict__ bias, unsigned short* __restrict__ xw,
    float* __restrict__ out) {
  extern __shared__ char smem[];
  gemm_body<FH, false>(smem, (int)blockIdx.x, A, Wt, bias, xw, out);
}

// ---------------- aggregation: no shfl chain, 4 gathers in flight ----------
// One wave per dst. lane = e(3b) | l8(3b): e = edge slot, l8 = feature chunk.
// Record: cnt<<25 | sv<<9 | r<<6 -> address = rec & 0x1FFFFFF, w = rcp(cnt).
template <bool RELU_BF16>
__global__ void __launch_bounds__(256) agg_csr(
    const int* __restrict__ row_start, const int* __restrict__ deg,
    const unsigned* __restrict__ recs, const unsigned short* __restrict__ xw,
    const float* __restrict__ root,
    float* __restrict__ out_f32, unsigned short* __restrict__ out_b16) {
  const int gid  = blockIdx.x * blockDim.x + threadIdx.x;
  const int lane = gid & 63;
  const int d    = gid >> 6;
  if (d >= NN) return;
  const int e  = lane >> 3;
  const int l8 = lane & 7;
  const int base = row_start[d];
  const int n    = deg[d];
  const unsigned* po = recs + base;
  const unsigned short* xp = xw + l8 * 8;
  float a[8] = {};

  for (int i0 = 0; i0 < n; i0 += 32) {
    const int i = i0 + e;
    // 4 slots per lane: i, i+8, i+16, i+24. Same-address 8-way broadcast loads.
    const unsigned r0 = (i      < n) ? po[i]      : 0u;
    const unsigned r1 = (i + 8  < n) ? po[i + 8]  : 0u;
    const unsigned r2 = (i + 16 < n) ? po[i + 16] : 0u;
    const unsigned r3 = (i + 24 < n) ? po[i + 24] : 0u;
    const unsigned u0 = min(r0 & 0x01FFFFFFu, XWMAX);
    const unsigned u1 = min(r1 & 0x01FFFFFFu, XWMAX);
    const unsigned u2 = min(r2 & 0x01FFFFFFu, XWMAX);
    const unsigned u3 = min(r3 & 0x01FFFFFFu, XWMAX);
    const bf16x8 v0 = *(const bf16x8*)(xp + u0);
    const bf16x8 v1 = *(const bf16x8*)(xp + u1);
    const bf16x8 v2 = *(const bf16x8*)(xp + u2);
    const bf16x8 v3 = *(const bf16x8*)(xp + u3);
    float w0 = __builtin_amdgcn_rcpf((float)(r0 >> 25));
    float w1 = __builtin_amdgcn_rcpf((float)(r1 >> 25));
    float w2 = __builtin_amdgcn_rcpf((float)(r2 >> 25));
    float w3 = __builtin_amdgcn_rcpf((float)(r3 >> 25));
    if (i      >= n) w0 = 0.f;
    if (i + 8  >= n) w1 = 0.f;
    if (i + 16 >= n) w2 = 0.f;
    if (i + 24 >= n) w3 = 0.f;
#pragma unroll
    for (int q = 0; q < 8; ++q) a[q] += bf2f((unsigned short)v0[q]) * w0;
#pragma unroll
    for (int q = 0; q < 8; ++q) a[q] += bf2f((unsigned short)v1[q]) * w1;
#pragma unroll
    for (int q = 0; q < 8; ++q) a[q] += bf2f((unsigned short)v2[q]) * w2;
#pragma unroll
    for (int q = 0; q < 8; ++q) a[q] += bf2f((unsigned short)v3[q]) * w3;
  }

#pragma unroll
  for (int q = 0; q < 8; ++q) {
    a[q] += __shfl_xor(a[q], 8, 64);
    a[q] += __shfl_xor(a[q], 16, 64);
    a[q] += __shfl_xor(a[q], 32, 64);
  }

  if (e == 0) {
    const float4 r0 = *(const float4*)(root + (size_t)d * 64 + l8 * 8);
    const float4 r1 = *(const float4*)(root + (size_t)d * 64 + l8 * 8 + 4);
    const float o[8] = {r0.x + a[0], r0.y + a[1], r0.z + a[2], r0.w + a[3],
                        r1.x + a[4], r1.y + a[5], r1.z + a[6], r1.w + a[7]};
    if (RELU_BF16) {
      bf16x8 ov;
#pragma unroll
      for (int q = 0; q < 8; ++q) ov[q] = (short)f2bf(fmaxf(o[q], 0.f));
      *(bf16x8*)(out_b16 + (size_t)d * 64 + l8 * 8) = ov;
    } else {
      *(float4*)(out_f32 + (size_t)d * 64 + l8 * 8)     = make_float4(o[0], o[1], o[2], o[3]);
      *(float4*)(out_f32 + (size_t)d * 64 + l8 * 8 + 4) = make_float4(o[4], o[5], o[6], o[7]);
    }
  }
}

extern "C" void kernel_launch(void* const* d_in, const int* in_sizes, int n_in,
                              void* d_out, int out_size, void* d_ws, size_t ws_size,
                              hipStream_t stream) {
  const float* x   = (const float*)d_in[0];
  const int*   ei  = (const int*)d_in[1];
  const int*   et  = (const int*)d_in[2];
  const float* W1r = (const float*)d_in[3];
  const float* W1o = (const float*)d_in[4];
  const float* b1  = (const float*)d_in[5];
  const float* W2r = (const float*)d_in[6];
  const float* W2o = (const float*)d_in[7];
  const float* b2  = (const float*)d_in[8];
  float* out = (float*)d_out;

  const int* src = ei;
  const int* dst = ei + NE;

  char* ws = (char*)d_ws;
  size_t off = 0;
  auto alloc = [&](size_t bytes) {
    void* p = ws + off; off += (bytes + 255) & ~(size_t)255; return p;
  };
  int*   bcur      = (int*)alloc((size_t)NB * 4);
  int*   row_start = (int*)alloc((size_t)NN * 4);
  int*   deg       = (int*)alloc((size_t)NN * 4);
  unsigned* brecs  = (unsigned*)alloc((size_t)NB * CAP * 4);              //  9.6 MB
  unsigned* offs   = (unsigned*)alloc((size_t)NB * CAP * 4);              //  9.6 MB
  unsigned short* xw    = (unsigned short*)alloc((size_t)NN * NR * 64 * 2); // 51.2 MB
  unsigned short* hb    = (unsigned short*)alloc((size_t)NN * FH * 2);      //  6.4 MB
  float*          hroot = (float*)alloc((size_t)NN * 64 * 4);               // 12.8 MB
  unsigned short* Wt1   = (unsigned short*)alloc((size_t)(NR + 1) * 64 * FIN * 2);
  unsigned short* Wt2   = (unsigned short*)alloc((size_t)(NR + 1) * 64 * FH * 2);

  const int nprep = (NR + 1) * 64 * (FIN + FH);
  prep<<<(nprep + 255) / 256, 256, 0, stream>>>(W1r, W1o, W2r, W2o, Wt1, Wt2, bcur);

  const int gemm_blocks = (NN + 63) / 64;
  const int agg_blocks  = (NN * 64 + 255) / 256;
  constexpr int SM1 = 3 * 64 * (FIN + 8) * 2;   // 52224 B (>= append's 39040)
  constexpr int SM2 = 3 * 64 * (FH + 8) * 2;    // 27648 B

  // Layer 1 transform || CSR append (independent), then finalize.
  fused_append_gemm1<<<NAPP + gemm_blocks, 256, SM1, stream>>>(
      src, dst, et, bcur, brecs, x, Wt1, b1, xw, hroot);
  bucket_finalize<<<NB, 256, 0, stream>>>(bcur, brecs, row_start, deg, offs);

  // Layer 1 aggregate, Layer 2 transform + aggregate.
  agg_csr<true><<<agg_blocks, 256, 0, stream>>>(row_start, deg, offs, xw, hroot, nullptr, hb);
  gemm_l2<<<gemm_blocks, 256, SM2, stream>>>(hb, Wt2, b2, xw, out);
  agg_csr<false><<<agg_blocks, 256, 0, stream>>>(row_start, deg, offs, xw, out, out, nullptr);
}

// Round 2
// 239.406 us; speedup vs baseline: 1.0595x; 1.0162x over previous
//
#include <hip/hip_runtime.h>

// RGCN: N=50000, E=1.6M, R=8, 128 -> 64 -> 64.
// R14 = R13 (243.3us) with fused-dispatch overhaul:
//   - gemm: A-fragments live in registers (g-invariant across the 9 weight
//     groups) -> As LDS tile + staging pass + one barrier deleted. LDS is now
//     B-dbuf only (34.8KB K=128 / 18.4KB K=64).
//   - fused dispatch LDS 52224 -> 39040 (append's need): 3 -> 4 blocks/CU.
//   - append blocks interleaved (blockIdx%3==2) instead of first, so every
//     CU runs a gemm/append mix and the overlap actually happens.
//   - agg: 8 gather slots in flight for deg>32 rows (4-slot tail for <=32).

constexpr int NN  = 50000;
constexpr int NE  = 1600000;
constexpr int NR  = 8;
constexpr int FIN = 128;
constexpr int FH  = 64;

constexpr int BSH = 7;                       // 128 dst nodes per bucket
constexpr int BN  = 1 << BSH;
constexpr int NB  = (NN + BN - 1) >> BSH;    // 391
constexpr int CAP = 6144;                    // bucket capacity (load ~4092±64)
constexpr int CH  = 4096;                    // edges per append block
constexpr int NAPP = (NE + CH - 1) / CH;     // 391 append blocks
constexpr unsigned XWMAX = (unsigned)(NN - 1) * (NR * 64) + (NR - 1) * 64;

typedef __attribute__((ext_vector_type(8))) short bf16x8;
typedef __attribute__((ext_vector_type(4))) float f32x4;

__device__ __forceinline__ unsigned short f2bf(float f) {
  unsigned u = __float_as_uint(f);
  u = (u + 0x7fff + ((u >> 16) & 1)) >> 16;   // RNE
  return (unsigned short)u;
}
__device__ __forceinline__ float bf2f(unsigned short b) {
  return __uint_as_float(((unsigned)b) << 16);
}
__device__ __forceinline__ bool edge_ok(unsigned s, unsigned d, unsigned r) {
  return s < NN && d < NN && r < NR;
}

// ---------------- CSR build: append (device body, LDS via pointer) ----------
// LDS: stage[CH] (32768B) | h[NB] | gbase[NB] | sbase[NB] | scur[NB] | wtot[4]
// = 39040 B total.
__device__ void append_body(char* smem, int bx,
                            const int* __restrict__ src,
                            const int* __restrict__ dst,
                            const int* __restrict__ et,
                            int* __restrict__ bcur,
                            unsigned* __restrict__ brecs) {
  uint2* stage = (uint2*)smem;
  int* h     = (int*)(smem + (size_t)CH * 8);
  int* gbase = h + NB;
  int* sbase = gbase + NB;
  int* scur  = sbase + NB;
  int* wtot  = scur + NB;

  const int t  = threadIdx.x;
  const int c0 = bx * CH;
  const int m  = min(CH, NE - c0);

  for (int i = t; i < NB; i += 256) h[i] = 0;
  __syncthreads();

  // pass A: per-block bucket histogram
  for (int i = t; i < m; i += 256) {
    const unsigned s = (unsigned)src[c0 + i];
    const unsigned d = (unsigned)dst[c0 + i];
    const unsigned r = (unsigned)et[c0 + i];
    if (edge_ok(s, d, r)) atomicAdd(&h[d >> BSH], 1);
  }
  __syncthreads();

  // reserve spans + block-local exclusive scan (2 buckets per thread)
  const int v0 = (2 * t < NB) ? h[2 * t] : 0;
  const int v1 = (2 * t + 1 < NB) ? h[2 * t + 1] : 0;
  if (2 * t < NB     && v0) gbase[2 * t]     = atomicAdd(&bcur[2 * t], v0);
  if (2 * t + 1 < NB && v1) gbase[2 * t + 1] = atomicAdd(&bcur[2 * t + 1], v1);
  const int s = v0 + v1;
  int incl = s;
#pragma unroll
  for (int o = 1; o < 64; o <<= 1) {
    int u = __shfl_up(incl, o, 64);
    if ((t & 63) >= o) incl += u;
  }
  if ((t & 63) == 63) wtot[t >> 6] = incl;
  __syncthreads();
  int wo = 0;
  for (int w = 0; w < (t >> 6); ++w) wo += wtot[w];
  const int e = wo + incl - s;
  if (2 * t < NB)     { sbase[2 * t] = e;          scur[2 * t] = e; }
  if (2 * t + 1 < NB) { sbase[2 * t + 1] = e + v0; scur[2 * t + 1] = e + v0; }
  __syncthreads();

  // pass B: stage records grouped by bucket
  for (int i = t; i < m; i += 256) {
    const unsigned sv = (unsigned)src[c0 + i];
    const unsigned d  = (unsigned)dst[c0 + i];
    const unsigned r  = (unsigned)et[c0 + i];
    if (edge_ok(sv, d, r)) {
      const int p = atomicAdd(&scur[d >> BSH], 1);
      if (p < CH) stage[p] = make_uint2((sv << 10) | (((unsigned)d & (BN - 1)) << 3) | r, d);
    }
  }
  __syncthreads();

  // write-out: consecutive j -> consecutive global addresses (4B packed)
  const int M = min(sbase[NB - 1] + h[NB - 1], CH);
  for (int j = t; j < M; j += 256) {
    const uint2 rec = stage[j];
    const int b = (int)(rec.y >> BSH);
    const int idx = min(gbase[b] + (j - sbase[b]), NB * CAP - 1);
    brecs[idx] = rec.x;
  }
}

// One block per bucket: count per (dlocal, r) in LDS, scan, emit
// deg/row_start, place final 4B records (cnt<<25 | sv<<9 | r<<6) into the
// bucket window. Weight = 1/cnt recovered in agg via v_rcp; no inv[] table.
__global__ void __launch_bounds__(256) bucket_finalize(
    const int* __restrict__ bcur, const unsigned* __restrict__ brecs,
    int* __restrict__ row_start, int* __restrict__ deg,
    unsigned* __restrict__ recs) {
  const int b    = blockIdx.x;
  const int base = b * CAP;
  const int m    = min(bcur[b] - base, CAP);
  const int d0   = b << BSH;
  __shared__ int cnt[BN * NR];
  __shared__ int curs[BN * NR];
  __shared__ int wtot[4];
  const int t = threadIdx.x;

  for (int i = t; i < BN * NR; i += 256) cnt[i] = 0;
  __syncthreads();
  for (int i = t; i < m; i += 256) {
    const unsigned rec = brecs[base + i];
    const int dl = (int)((rec >> 3) & (BN - 1));
    const int r  = (int)(rec & 7);
    atomicAdd(&cnt[dl * NR + r], 1);
  }
  __syncthreads();

  const int c0 = cnt[t * 4], c1 = cnt[t * 4 + 1], c2 = cnt[t * 4 + 2], c3 = cnt[t * 4 + 3];
  const int s = c0 + c1 + c2 + c3;
  int incl = s;
#pragma unroll
  for (int o = 1; o < 64; o <<= 1) {
    int u = __shfl_up(incl, o, 64);
    if ((t & 63) >= o) incl += u;
  }
  if ((t & 63) == 63) wtot[t >> 6] = incl;
  __syncthreads();
  int wo = 0;
  for (int w = 0; w < (t >> 6); ++w) wo += wtot[w];
  const int e = wo + incl - s;
  curs[t * 4]     = e;
  curs[t * 4 + 1] = e + c0;
  curs[t * 4 + 2] = e + c0 + c1;
  curs[t * 4 + 3] = e + c0 + c1 + c2;
  __syncthreads();

  if (t < BN) {
    const int d = d0 + t;
    if (d < NN) {
      const int start = curs[t * NR];
      const int end   = (t == BN - 1) ? m : curs[(t + 1) * NR];
      row_start[d] = base + start;
      deg[d]       = end - start;
    }
  }
  __syncthreads();

  for (int i = t; i < m; i += 256) {
    const unsigned rec = brecs[base + i];
    const int dl = (int)((rec >> 3) & (BN - 1));
    const int r  = (int)(rec & 7);
    const unsigned sv = rec >> 10;
    const int p  = atomicAdd(&curs[dl * NR + r], 1);
    const unsigned cn = (unsigned)min(cnt[dl * NR + r], 127);
    recs[base + min(p, CAP - 1)] = (cn << 25) | (sv << 9) | ((unsigned)r << 6);
  }
}

// ---------------- prep: bcur init + weights -> bf16 transposed ----------------
__global__ void prep(const float* __restrict__ W1r, const float* __restrict__ W1o,
                     const float* __restrict__ W2r, const float* __restrict__ W2o,
                     unsigned short* __restrict__ Wt1,
                     unsigned short* __restrict__ Wt2,
                     int* __restrict__ bcur) {
  const int i  = blockIdx.x * blockDim.x + threadIdx.x;
  if (i < NB) bcur[i] = i * CAP;
  const int n1 = (NR + 1) * 64 * FIN;
  const int n2 = (NR + 1) * 64 * FH;
  if (i < n1) {
    const int g = i / (64 * FIN), rem = i % (64 * FIN);
    const int n = rem / FIN, k = rem % FIN;
    const float* W = (g < NR) ? (W1r + (size_t)g * FIN * 64) : W1o;
    Wt1[i] = f2bf(W[k * 64 + n]);
  } else if (i < n1 + n2) {
    const int j = i - n1;
    const int g = j / (64 * FH), rem = j % (64 * FH);
    const int n = rem / FH, k = rem % FH;
    const float* W = (g < NR) ? (W2r + (size_t)g * FH * 64) : W2o;
    Wt2[j] = f2bf(W[k * 64 + n]);
  }
}

// ---------------- MFMA GEMM body: A in registers, B-dbuf in LDS ------------
// A fragments are invariant across the 9 weight groups -> load once per lane
// from global (wave covers each row exactly once; no overfetch).
template <int K, bool A_FP32>
__device__ void gemm_body(char* smem, int bx,
                          const void* __restrict__ Av,
                          const unsigned short* __restrict__ Wt,
                          const float* __restrict__ bias,
                          unsigned short* __restrict__ xw,
                          float* __restrict__ root_out) {
  constexpr int KP  = K + 8;
  constexpr int NCH = 64 * (K / 8) / 256;   // B chunks per thread (4 / 2)
  constexpr int NKC = K / 32;               // MFMA K-steps (4 / 2)
  unsigned short* Bs0 = (unsigned short*)smem;   // dbuf halves: 2 x 64*KP
  const int n0  = bx * 64;
  const int tid = threadIdx.x;
  const int wave = tid >> 6, lane = tid & 63;
  const int i16 = lane & 15, quad = lane >> 4;
  const int r0 = wave * 16 + i16;
  const int arow = n0 + r0;

  // A fragments -> registers
  bf16x8 afrag[NKC];
  if constexpr (A_FP32) {
    const float* A = (const float*)Av;
#pragma unroll
    for (int kc = 0; kc < NKC; ++kc) {
      bf16x8 v = {};
      if (arow < NN) {
        const float* p = A + (size_t)arow * K + kc * 32 + quad * 8;
        const float4 f0 = *(const float4*)p;
        const float4 f1 = *(const float4*)(p + 4);
        v[0] = f2bf(f0.x); v[1] = f2bf(f0.y); v[2] = f2bf(f0.z); v[3] = f2bf(f0.w);
        v[4] = f2bf(f1.x); v[5] = f2bf(f1.y); v[6] = f2bf(f1.z); v[7] = f2bf(f1.w);
      }
      afrag[kc] = v;
    }
  } else {
    const unsigned short* A = (const unsigned short*)Av;
#pragma unroll
    for (int kc = 0; kc < NKC; ++kc) {
      bf16x8 v = {};
      if (arow < NN) v = *(const bf16x8*)(A + (size_t)arow * K + kc * 32 + quad * 8);
      afrag[kc] = v;
    }
  }

  // stage B group 0 into buffer 0
  for (int c = 0; c < NCH; ++c) {
    const int idx = tid + c * 256;
    const int row = idx / (K / 8), kp = (idx % (K / 8)) * 8;
    *(bf16x8*)(Bs0 + row * KP + kp) = *(const bf16x8*)(Wt + idx * 8);
  }
  __syncthreads();

  for (int g = 0; g <= NR; ++g) {
    const int buf = g & 1;
    unsigned short* Bc = Bs0 + buf * 64 * KP;         // compute buffer
    unsigned short* Bn = Bs0 + (buf ^ 1) * 64 * KP;   // next buffer
    bf16x8 breg[NCH];
    if (g < NR) {
      const unsigned short* Wn = Wt + (size_t)(g + 1) * 64 * K;
#pragma unroll
      for (int c = 0; c < NCH; ++c) breg[c] = *(const bf16x8*)(Wn + (tid + c * 256) * 8);
    }

    f32x4 acc[4] = {};
#pragma unroll
    for (int kc = 0; kc < NKC; ++kc) {
      const int k0 = kc * 32 + quad * 8;
      const bf16x8 a0 = afrag[kc];
      const bf16x8 b0 = *(const bf16x8*)(Bc + (i16)      * KP + k0);
      const bf16x8 b1 = *(const bf16x8*)(Bc + (i16 + 16) * KP + k0);
      const bf16x8 b2 = *(const bf16x8*)(Bc + (i16 + 32) * KP + k0);
      const bf16x8 b3 = *(const bf16x8*)(Bc + (i16 + 48) * KP + k0);
      acc[0] = __builtin_amdgcn_mfma_f32_16x16x32_bf16(a0, b0, acc[0], 0, 0, 0);
      acc[1] = __builtin_amdgcn_mfma_f32_16x16x32_bf16(a0, b1, acc[1], 0, 0, 0);
      acc[2] = __builtin_amdgcn_mfma_f32_16x16x32_bf16(a0, b2, acc[2], 0, 0, 0);
      acc[3] = __builtin_amdgcn_mfma_f32_16x16x32_bf16(a0, b3, acc[3], 0, 0, 0);
    }

    if (g < NR) {
#pragma unroll
      for (int c = 0; c < NCH; ++c) {
        const int idx = tid + c * 256;
        const int row = idx / (K / 8), kp = (idx % (K / 8)) * 8;
        *(bf16x8*)(Bn + row * KP + kp) = breg[c];
      }
#pragma unroll
      for (int reg = 0; reg < 4; ++reg) {
        const int n = n0 + wave * 16 + quad * 4 + reg;
        if (n >= NN) continue;
        unsigned short* p = xw + (size_t)n * (NR * 64) + g * 64 + i16;
#pragma unroll
        for (int ct = 0; ct < 4; ++ct) p[ct * 16] = f2bf(acc[ct][reg]);
      }
    } else {
      float bv[4];
#pragma unroll
      for (int ct = 0; ct < 4; ++ct) bv[ct] = bias[ct * 16 + i16];
#pragma unroll
      for (int reg = 0; reg < 4; ++reg) {
        const int n = n0 + wave * 16 + quad * 4 + reg;
        if (n >= NN) continue;
        float* p = root_out + (size_t)n * 64 + i16;
#pragma unroll
        for (int ct = 0; ct < 4; ++ct) p[ct * 16] = acc[ct][reg] + bv[ct];
      }
    }
    __syncthreads();
  }
}

// ---------------- fused dispatch: append interleaved with gemm1 -------------
// blockIdx%3==2 -> append (391 of them, ids bx/3); others -> gemm
// (id = bx - (appends before bx) = bx - (bx+1)/3).
__global__ void __launch_bounds__(256) fused_append_gemm1(
    const int* __restrict__ src, const int* __restrict__ dst,
    const int* __restrict__ et, int* __restrict__ bcur,
    unsigned* __restrict__ brecs,
    const float* __restrict__ A, const unsigned short* __restrict__ Wt,
    const float* __restrict__ bias, unsigned short* __restrict__ xw,
    float* __restrict__ root_out) {
  extern __shared__ char smem[];
  const int bx = (int)blockIdx.x;
  if (bx % 3 == 2 && bx / 3 < NAPP)
    append_body(smem, bx / 3, src, dst, et, bcur, brecs);
  else
    gemm_body<FIN, true>(smem, bx - (bx + 1) / 3, A, Wt, bias, xw, root_out);
}

__global__ void __launch_bounds__(256) gemm_l2(
    const unsigned short* __restrict__ A, const unsigned short* __restrict__ Wt,
    const float* __restrict__ bias, unsigned short* __restrict__ xw,
    float* __restrict__ out) {
  extern __shared__ char smem[];
  gemm_body<FH, false>(smem, (int)blockIdx.x, A, Wt, bias, xw, out);
}

// ---------------- aggregation: up to 8 gathers in flight --------------------
// One wave per dst. lane = e(3b) | l8(3b): e = edge slot, l8 = feature chunk.
// Record: cnt<<25 | sv<<9 | r<<6 -> address = rec & 0x1FFFFFF, w = rcp(cnt).
template <bool RELU_BF16>
__global__ void __launch_bounds__(256) agg_csr(
    const int* __restrict__ row_start, const int* __restrict__ deg,
    const unsigned* __restrict__ recs, const unsigned short* __restrict__ xw,
    const float* __restrict__ root,
    float* __restrict__ out_f32, unsigned short* __restrict__ out_b16) {
  const int gid  = blockIdx.x * blockDim.x + threadIdx.x;
  const int lane = gid & 63;
  const int d    = gid >> 6;
  if (d >= NN) return;
  const int e  = lane >> 3;
  const int l8 = lane & 7;
  const int base = row_start[d];
  const int n    = deg[d];
  const unsigned* po = recs + base;
  const unsigned short* xp = xw + l8 * 8;
  float a[8] = {};

  int i0 = 0;
  // 64-edge iterations while >32 edges remain: 8 gathers in flight per lane.
  for (; i0 + 32 < n; i0 += 64) {
    unsigned rr[8];
#pragma unroll
    for (int sl = 0; sl < 8; ++sl) {
      const int i = i0 + e + 8 * sl;
      rr[sl] = (i < n) ? po[i] : 0u;
    }
    bf16x8 vv[8];
#pragma unroll
    for (int sl = 0; sl < 8; ++sl) {
      const unsigned u = min(rr[sl] & 0x01FFFFFFu, XWMAX);
      vv[sl] = *(const bf16x8*)(xp + u);
    }
#pragma unroll
    for (int sl = 0; sl < 8; ++sl) {
      float w = __builtin_amdgcn_rcpf((float)(rr[sl] >> 25));
      if (i0 + e + 8 * sl >= n) w = 0.f;
#pragma unroll
      for (int q = 0; q < 8; ++q) a[q] += bf2f((unsigned short)vv[sl][q]) * w;
    }
  }
  // tail: <=32 edges, 4 slots.
  if (i0 < n) {
    const int i = i0 + e;
    const unsigned r0 = (i      < n) ? po[i]      : 0u;
    const unsigned r1 = (i + 8  < n) ? po[i + 8]  : 0u;
    const unsigned r2 = (i + 16 < n) ? po[i + 16] : 0u;
    const unsigned r3 = (i + 24 < n) ? po[i + 24] : 0u;
    const unsigned u0 = min(r0 & 0x01FFFFFFu, XWMAX);
    const unsigned u1 = min(r1 & 0x01FFFFFFu, XWMAX);
    const unsigned u2 = min(r2 & 0x01FFFFFFu, XWMAX);
    const unsigned u3 = min(r3 & 0x01FFFFFFu, XWMAX);
    const bf16x8 v0 = *(const bf16x8*)(xp + u0);
    const bf16x8 v1 = *(const bf16x8*)(xp + u1);
    const bf16x8 v2 = *(const bf16x8*)(xp + u2);
    const bf16x8 v3 = *(const bf16x8*)(xp + u3);
    float w0 = __builtin_amdgcn_rcpf((float)(r0 >> 25));
    float w1 = __builtin_amdgcn_rcpf((float)(r1 >> 25));
    float w2 = __builtin_amdgcn_rcpf((float)(r2 >> 25));
    float w3 = __builtin_amdgcn_rcpf((float)(r3 >> 25));
    if (i      >= n) w0 = 0.f;
    if (i + 8  >= n) w1 = 0.f;
    if (i + 16 >= n) w2 = 0.f;
    if (i + 24 >= n) w3 = 0.f;
#pragma unroll
    for (int q = 0; q < 8; ++q) a[q] += bf2f((unsigned short)v0[q]) * w0;
#pragma unroll
    for (int q = 0; q < 8; ++q) a[q] += bf2f((unsigned short)v1[q]) * w1;
#pragma unroll
    for (int q = 0; q < 8; ++q) a[q] += bf2f((unsigned short)v2[q]) * w2;
#pragma unroll
    for (int q = 0; q < 8; ++q) a[q] += bf2f((unsigned short)v3[q]) * w3;
  }

#pragma unroll
  for (int q = 0; q < 8; ++q) {
    a[q] += __shfl_xor(a[q], 8, 64);
    a[q] += __shfl_xor(a[q], 16, 64);
    a[q] += __shfl_xor(a[q], 32, 64);
  }

  if (e == 0) {
    const float4 r0 = *(const float4*)(root + (size_t)d * 64 + l8 * 8);
    const float4 r1 = *(const float4*)(root + (size_t)d * 64 + l8 * 8 + 4);
    const float o[8] = {r0.x + a[0], r0.y + a[1], r0.z + a[2], r0.w + a[3],
                        r1.x + a[4], r1.y + a[5], r1.z + a[6], r1.w + a[7]};
    if (RELU_BF16) {
      bf16x8 ov;
#pragma unroll
      for (int q = 0; q < 8; ++q) ov[q] = (short)f2bf(fmaxf(o[q], 0.f));
      *(bf16x8*)(out_b16 + (size_t)d * 64 + l8 * 8) = ov;
    } else {
      *(float4*)(out_f32 + (size_t)d * 64 + l8 * 8)     = make_float4(o[0], o[1], o[2], o[3]);
      *(float4*)(out_f32 + (size_t)d * 64 + l8 * 8 + 4) = make_float4(o[4], o[5], o[6], o[7]);
    }
  }
}

extern "C" void kernel_launch(void* const* d_in, const int* in_sizes, int n_in,
                              void* d_out, int out_size, void* d_ws, size_t ws_size,
                              hipStream_t stream) {
  const float* x   = (const float*)d_in[0];
  const int*   ei  = (const int*)d_in[1];
  const int*   et  = (const int*)d_in[2];
  const float* W1r = (const float*)d_in[3];
  const float* W1o = (const float*)d_in[4];
  const float* b1  = (const float*)d_in[5];
  const float* W2r = (const float*)d_in[6];
  const float* W2o = (const float*)d_in[7];
  const float* b2  = (const float*)d_in[8];
  float* out = (float*)d_out;

  const int* src = ei;
  const int* dst = ei + NE;

  char* ws = (char*)d_ws;
  size_t off = 0;
  auto alloc = [&](size_t bytes) {
    void* p = ws + off; off += (bytes + 255) & ~(size_t)255; return p;
  };
  int*   bcur      = (int*)alloc((size_t)NB * 4);
  int*   row_start = (int*)alloc((size_t)NN * 4);
  int*   deg       = (int*)alloc((size_t)NN * 4);
  unsigned* brecs  = (unsigned*)alloc((size_t)NB * CAP * 4);              //  9.6 MB
  unsigned* offs   = (unsigned*)alloc((size_t)NB * CAP * 4);              //  9.6 MB
  unsigned short* xw    = (unsigned short*)alloc((size_t)NN * NR * 64 * 2); // 51.2 MB
  unsigned short* hb    = (unsigned short*)alloc((size_t)NN * FH * 2);      //  6.4 MB
  float*          hroot = (float*)alloc((size_t)NN * 64 * 4);               // 12.8 MB
  unsigned short* Wt1   = (unsigned short*)alloc((size_t)(NR + 1) * 64 * FIN * 2);
  unsigned short* Wt2   = (unsigned short*)alloc((size_t)(NR + 1) * 64 * FH * 2);

  const int nprep = (NR + 1) * 64 * (FIN + FH);
  prep<<<(nprep + 255) / 256, 256, 0, stream>>>(W1r, W1o, W2r, W2o, Wt1, Wt2, bcur);

  const int gemm_blocks = (NN + 63) / 64;
  const int agg_blocks  = (NN * 64 + 255) / 256;
  constexpr int SM1 = CH * 8 + 4 * NB * 4 + 16;          // 39040 (append need >= gemm 34816)
  constexpr int SM2 = 2 * 64 * (FH + 8) * 2;             // 18432

  // Layer 1 transform || CSR append (interleaved roles), then finalize.
  fused_append_gemm1<<<NAPP + gemm_blocks, 256, SM1, stream>>>(
      src, dst, et, bcur, brecs, x, Wt1, b1, xw, hroot);
  bucket_finalize<<<NB, 256, 0, stream>>>(bcur, brecs, row_start, deg, offs);

  // Layer 1 aggregate, Layer 2 transform + aggregate.
  agg_csr<true><<<agg_blocks, 256, 0, stream>>>(row_start, deg, offs, xw, hroot, nullptr, hb);
  gemm_l2<<<gemm_blocks, 256, SM2, stream>>>(hb, Wt2, b2, xw, out);
  agg_csr<false><<<agg_blocks, 256, 0, stream>>>(row_start, deg, offs, xw, out, out, nullptr);
}